// Round 1
// baseline (3285.028 us; speedup 1.0000x reference)
//
#include <hip/hip_runtime.h>

// ---------------------------------------------------------------------------
// HierarchicalBiLSTM_CRF on MI355X (gfx950)
//
// Pipeline (all bf16 MFMA matmuls, fp32 state/activations):
//  K0a prep_weights : cast/pad weights to bf16
//  K0b prep_small   : clens, last-token ids, counting-sort seqs by len (desc)
//  K1  gemm_bf      : proj[30000][1024] = emb x tok_Wih_f^T   (vocab pre-proj)
//  K3  gemm_bf      : gxb[1024][1024]   = emb[last tok] x tok_Wih_b^T
//  K4  bwd_step     : 1-step reverse LSTM (masked reverse scan == single step
//                     from zero state at t = clen-1)  -> chunks[:,256:512]
//  K5  tok_fwd      : forward token LSTM recurrence, 32 blocks x 32 seqs,
//                     gx gathered from proj per step  -> chunks[:,0:256]
//  K6  gemm_bf x2   : gxc_{f,b} = chunks x chk_Wih_{f,b}^T
//  K7  chunk_rec    : chunk BiLSTM (fwd+bwd as 2 blocks) -> ch[1024][512] bf16
//  K8  fc_kernel    : out = ch x fc_W^T + fc_b
// ---------------------------------------------------------------------------

typedef __attribute__((ext_vector_type(8))) short s16x8;
typedef __attribute__((ext_vector_type(4))) float f32x4;

__device__ __forceinline__ unsigned short f2bf(float f) {
  unsigned u = __builtin_bit_cast(unsigned, f);
  u += 0x7fff + ((u >> 16) & 1);   // RNE
  return (unsigned short)(u >> 16);
}
__device__ __forceinline__ float bf2f(unsigned short h) {
  unsigned u = ((unsigned)h) << 16;
  return __builtin_bit_cast(float, u);
}
__device__ __forceinline__ float sigm(float x) { return 1.f / (1.f + __expf(-x)); }
__device__ __forceinline__ float tanh_(float x) { return 1.f - 2.f / (__expf(2.f * x) + 1.f); }

union PK8 { s16x8 v; unsigned short u[8]; };

// ---------------------------------------------------------------------------
// K0a: cast weights to bf16 (pad K 300->320 for token Wih)
__global__ void prep_weights(const float* __restrict__ wihf, const float* __restrict__ wihb,
                             const float* __restrict__ whhf,
                             const float* __restrict__ wcf, const float* __restrict__ wcb,
                             const float* __restrict__ whcf, const float* __restrict__ whcb,
                             unsigned short* __restrict__ o_wf, unsigned short* __restrict__ o_wb,
                             unsigned short* __restrict__ o_whhf,
                             unsigned short* __restrict__ o_wcf, unsigned short* __restrict__ o_wcb,
                             unsigned short* __restrict__ o_whcf, unsigned short* __restrict__ o_whcb) {
  const int job = blockIdx.y, r = blockIdx.x, tid = threadIdx.x;
  const float* src; unsigned short* dst; int Ks, Kd;
  switch (job) {
    case 0: src = wihf; dst = o_wf;   Ks = 300; Kd = 320; break;
    case 1: src = wihb; dst = o_wb;   Ks = 300; Kd = 320; break;
    case 2: src = whhf; dst = o_whhf; Ks = 256; Kd = 256; break;
    case 3: src = wcf;  dst = o_wcf;  Ks = 512; Kd = 512; break;
    case 4: src = wcb;  dst = o_wcb;  Ks = 512; Kd = 512; break;
    case 5: src = whcf; dst = o_whcf; Ks = 256; Kd = 256; break;
    default:src = whcb; dst = o_whcb; Ks = 256; Kd = 256; break;
  }
  for (int c = tid; c < Kd; c += 256)
    dst[r * Kd + c] = f2bf(c < Ks ? src[r * Ks + c] : 0.f);
}

// ---------------------------------------------------------------------------
// K0b: lengths, last tokens, counting sort (descending by len), group maxes
__global__ void prep_small(const int* __restrict__ x, const int* __restrict__ xcl,
                           int* __restrict__ clens, int* __restrict__ lastv,
                           int* __restrict__ order, int* __restrict__ glen) {
  __shared__ int start[65];
  const int n = threadIdx.x;  // 1024 threads
  if (n < 65) start[n] = 0;
  __syncthreads();
  int len = xcl[n]; len = len < 1 ? 1 : (len > 64 ? 64 : len);
  clens[n] = len;
  lastv[n] = x[n * 64 + len - 1];
  atomicAdd(&start[len], 1);
  __syncthreads();
  if (n == 0) {
    int acc = 0;
    for (int l = 64; l >= 1; --l) { int h = start[l]; start[l] = acc; acc += h; }
  }
  __syncthreads();
  int pos = atomicAdd(&start[len], 1);
  order[pos] = n;
  __syncthreads();
  if (n < 32) glen[n] = clens[order[n * 32]];   // descending -> first = group max
}

// ---------------------------------------------------------------------------
// Unified GEMM: C[M][1024](bf16) = A(rows via rowmap)[M][Klog](f32) x B[1024][KP](bf16)^T
// block tile 128m x 256n, 256 threads (wave grid 2x2, wave = 64m x 128n).
// A staged f32->bf16 into LDS; B (weights) read straight from L2.
__global__ __launch_bounds__(256, 2)
void gemm_bf(const float* __restrict__ A, const int* __restrict__ rowmap,
             int Mrows, int Astride, int Klog, int KP,
             const unsigned short* __restrict__ B, unsigned short* __restrict__ C) {
  __shared__ unsigned short As[128 * 40];        // [128 rows][32 k] pad->40
  __shared__ unsigned short Ep[4][64 * 136];     // epilogue transpose, 16B-aligned rows
  const int tid = threadIdx.x;
  const int lane = tid & 63, w = tid >> 6;
  const int wrow = w >> 1, wcol = w & 1;
  const int cc = lane & 15, qq = lane >> 4;
  const int m0 = blockIdx.y * 128, n0 = blockIdx.x * 256;

  f32x4 zz = {0.f, 0.f, 0.f, 0.f};
  f32x4 acc[4][8];
#pragma unroll
  for (int i = 0; i < 4; ++i)
#pragma unroll
    for (int j = 0; j < 8; ++j) acc[i][j] = zz;

  const int arow = tid >> 1, ahalf = tid & 1;
  const float* arp = nullptr;
  {
    int av = m0 + arow;
    if (av < Mrows) {
      int amap = rowmap ? rowmap[av] : av;
      arp = A + (long)amap * Astride;
    }
  }

  const int nktiles = KP >> 5;
  for (int kt = 0; kt < nktiles; ++kt) {
    const int k0 = kt << 5;
    __syncthreads();
    {
      const int kb = k0 + ahalf * 16;
      unsigned short hv[16];
      if (arp && kb + 16 <= Klog) {
        const float* p = arp + kb;
#pragma unroll
        for (int i = 0; i < 16; i += 4) {
          f32x4 t = *(const f32x4*)(p + i);
          hv[i] = f2bf(t.x); hv[i + 1] = f2bf(t.y);
          hv[i + 2] = f2bf(t.z); hv[i + 3] = f2bf(t.w);
        }
      } else {
#pragma unroll
        for (int i = 0; i < 16; ++i) {
          float v = (arp && (kb + i) < Klog) ? arp[kb + i] : 0.f;
          hv[i] = f2bf(v);
        }
      }
      PK8 p0, p1;
#pragma unroll
      for (int i = 0; i < 8; ++i) { p0.u[i] = hv[i]; p1.u[i] = hv[8 + i]; }
      *(s16x8*)&As[arow * 40 + ahalf * 16] = p0.v;
      *(s16x8*)&As[arow * 40 + ahalf * 16 + 8] = p1.v;
    }
    __syncthreads();
    s16x8 af[4];
#pragma unroll
    for (int mt = 0; mt < 4; ++mt)
      af[mt] = *(const s16x8*)&As[(wrow * 64 + mt * 16 + cc) * 40 + qq * 8];
#pragma unroll
    for (int nt = 0; nt < 8; ++nt) {
      const unsigned short* bp = B + (long)(n0 + wcol * 128 + nt * 16 + cc) * KP + k0 + qq * 8;
      s16x8 bfr = *(const s16x8*)bp;
#pragma unroll
      for (int mt = 0; mt < 4; ++mt)
        acc[mt][nt] = __builtin_amdgcn_mfma_f32_16x16x32_bf16(af[mt], bfr, acc[mt][nt], 0, 0, 0);
    }
  }
  __syncthreads();
#pragma unroll
  for (int mt = 0; mt < 4; ++mt)
#pragma unroll
    for (int nt = 0; nt < 8; ++nt)
#pragma unroll
      for (int r = 0; r < 4; ++r)
        Ep[w][(mt * 16 + qq * 4 + r) * 136 + nt * 16 + cc] = f2bf(acc[mt][nt][r]);
  __syncthreads();
#pragma unroll
  for (int it = 0; it < 16; ++it) {
    int row = it * 4 + qq;
    s16x8 d = *(const s16x8*)&Ep[w][row * 136 + cc * 8];
    int gm = m0 + wrow * 64 + row;
    int gn = n0 + wcol * 128 + cc * 8;
    if (gm < Mrows) *(s16x8*)&C[(long)gm * 1024 + gn] = d;
  }
}

// ---------------------------------------------------------------------------
// K4: backward token "scan" = single step from zero state on last valid token.
__global__ void bwd_step(const unsigned short* __restrict__ gxb,
                         const float* __restrict__ bias,
                         float* __restrict__ chunks) {
  const int n = blockIdx.x, j = threadIdx.x;  // 1024 x 256
  const unsigned short* row = gxb + (long)n * 1024;
  float gi = bf2f(row[j]) + bias[j];
  float gg = bf2f(row[512 + j]) + bias[512 + j];
  float go = bf2f(row[768 + j]) + bias[768 + j];
  float cn = sigm(gi) * tanh_(gg);               // f gate multiplies c=0
  chunks[(long)n * 512 + 256 + j] = sigm(go) * tanh_(cn);
}

// ---------------------------------------------------------------------------
// K5: forward token LSTM recurrence. 32 blocks x 32 sorted seqs x 256 threads.
// gates[32][1024] = h[32][256] x Whh^T via 16x16x32 bf16 MFMA.
// Wave w owns n-tiles nt == w (mod 4): every lane ends up holding i,f,g,o for
// its (m,j) elements -> register-local c/h update, no cross-wave exchange.
__global__ __launch_bounds__(256, 1)
void tok_fwd(const unsigned short* __restrict__ proj,
             const unsigned short* __restrict__ Whh,
             const float* __restrict__ bias,
             const int* __restrict__ xtok,
             const int* __restrict__ order,
             const int* __restrict__ clens,
             const int* __restrict__ glen,
             float* __restrict__ chunks) {
  __shared__ unsigned short hly[32 * 264];  // h bf16 [32][256] pad->264
  __shared__ int sg[32], slen[32], stok[32];
  const int tid = threadIdx.x;
  const int lane = tid & 63, w = tid >> 6;
  const int cc = lane & 15, qq = lane >> 4;
  const int gb = blockIdx.x;

  if (tid < 32) {
    int s = order[gb * 32 + tid];
    sg[tid] = s;
    slen[tid] = clens[s];
  }
  for (int i = tid; i < 32 * 264; i += 256) hly[i] = 0;
  const int maxlen = glen[gb];
  __syncthreads();

  float bv[16];
#pragma unroll
  for (int tpe = 0; tpe < 4; ++tpe)
#pragma unroll
    for (int a = 0; a < 4; ++a)
      bv[tpe * 4 + a] = bias[tpe * 256 + (w + 4 * a) * 16 + cc];

  int lenr[8], seqr[8];
#pragma unroll
  for (int mt = 0; mt < 2; ++mt)
#pragma unroll
    for (int r = 0; r < 4; ++r) {
      int m = mt * 16 + qq * 4 + r;
      lenr[mt * 4 + r] = slen[m];
      seqr[mt * 4 + r] = sg[m];
    }

  float cst[32];
#pragma unroll
  for (int i = 0; i < 32; ++i) cst[i] = 0.f;

  f32x4 zz = {0.f, 0.f, 0.f, 0.f};

  for (int t = 0; t < maxlen; ++t) {
    __syncthreads();                       // prev-step h writes / stok reads done
    if (tid < 32) stok[tid] = xtok[sg[tid] * 64 + t];

    f32x4 acc[2][16];
#pragma unroll
    for (int mt = 0; mt < 2; ++mt)
#pragma unroll
      for (int i = 0; i < 16; ++i) acc[mt][i] = zz;

#pragma unroll
    for (int kt = 0; kt < 8; ++kt) {
      s16x8 a0 = *(const s16x8*)&hly[cc * 264 + kt * 32 + qq * 8];
      s16x8 a1 = *(const s16x8*)&hly[(16 + cc) * 264 + kt * 32 + qq * 8];
#pragma unroll
      for (int i = 0; i < 16; ++i) {
        const int nt = (i >> 2) * 16 + w + 4 * (i & 3);
        s16x8 bfr = *(const s16x8*)&Whh[(nt * 16 + cc) * 256 + kt * 32 + qq * 8];
        acc[0][i] = __builtin_amdgcn_mfma_f32_16x16x32_bf16(a0, bfr, acc[0][i], 0, 0, 0);
        acc[1][i] = __builtin_amdgcn_mfma_f32_16x16x32_bf16(a1, bfr, acc[1][i], 0, 0, 0);
      }
    }
    __syncthreads();                       // MFMA h reads done; stok visible

#pragma unroll
    for (int mt = 0; mt < 2; ++mt)
#pragma unroll
      for (int a = 0; a < 4; ++a) {
        const int j = (w + 4 * a) * 16 + cc;
#pragma unroll
        for (int r = 0; r < 4; ++r) {
          const int m = mt * 16 + qq * 4 + r;
          const int li = mt * 4 + r;
          const unsigned short* pr = proj + (long)stok[m] * 1024;
          float gi = acc[mt][a][r]      + bf2f(pr[j])       + bv[a];
          float gf = acc[mt][4 + a][r]  + bf2f(pr[256 + j]) + bv[4 + a];
          float gg = acc[mt][8 + a][r]  + bf2f(pr[512 + j]) + bv[8 + a];
          float go = acc[mt][12 + a][r] + bf2f(pr[768 + j]) + bv[12 + a];
          if (t < lenr[li]) {
            const int ci = mt * 16 + a * 4 + r;
            float cn = sigm(gf) * cst[ci] + sigm(gi) * tanh_(gg);
            cst[ci] = cn;
            float hn = sigm(go) * tanh_(cn);
            hly[m * 264 + j] = f2bf(hn);
            if (t == lenr[li] - 1) chunks[(long)seqr[li] * 512 + j] = hn;  // final h
          }
        }
      }
  }
}

// ---------------------------------------------------------------------------
// K7: chunk-level BiLSTM. blockIdx.x = direction (0 fwd, 1 bwd). 32 batch seqs.
__global__ __launch_bounds__(256, 1)
void chunk_rec(const unsigned short* __restrict__ gxf,
               const unsigned short* __restrict__ gxb,
               const unsigned short* __restrict__ Whf,
               const unsigned short* __restrict__ Whb,
               const float* __restrict__ bf_, const float* __restrict__ bb_,
               const int* __restrict__ xlen,
               unsigned short* __restrict__ ch) {
  __shared__ unsigned short hly[32 * 264];
  const int tid = threadIdx.x;
  const int lane = tid & 63, w = tid >> 6;
  const int cc = lane & 15, qq = lane >> 4;
  const int dir = blockIdx.x;
  const unsigned short* gx = dir ? gxb : gxf;
  const unsigned short* Whh = dir ? Whb : Whf;
  const float* bias = dir ? bb_ : bf_;

  for (int i = tid; i < 32 * 264; i += 256) hly[i] = 0;
  __syncthreads();

  float bv[16];
#pragma unroll
  for (int tpe = 0; tpe < 4; ++tpe)
#pragma unroll
    for (int a = 0; a < 4; ++a)
      bv[tpe * 4 + a] = bias[tpe * 256 + (w + 4 * a) * 16 + cc];

  int lenr[8];
#pragma unroll
  for (int mt = 0; mt < 2; ++mt)
#pragma unroll
    for (int r = 0; r < 4; ++r) {
      int m = mt * 16 + qq * 4 + r;
      int L = xlen[m];
      lenr[mt * 4 + r] = L > 32 ? 32 : L;
    }

  float cst[32];
#pragma unroll
  for (int i = 0; i < 32; ++i) cst[i] = 0.f;

  f32x4 zz = {0.f, 0.f, 0.f, 0.f};

  for (int tt = 0; tt < 32; ++tt) {
    const int t = dir ? (31 - tt) : tt;
    __syncthreads();

    f32x4 acc[2][16];
#pragma unroll
    for (int mt = 0; mt < 2; ++mt)
#pragma unroll
      for (int i = 0; i < 16; ++i) acc[mt][i] = zz;

#pragma unroll
    for (int kt = 0; kt < 8; ++kt) {
      s16x8 a0 = *(const s16x8*)&hly[cc * 264 + kt * 32 + qq * 8];
      s16x8 a1 = *(const s16x8*)&hly[(16 + cc) * 264 + kt * 32 + qq * 8];
#pragma unroll
      for (int i = 0; i < 16; ++i) {
        const int nt = (i >> 2) * 16 + w + 4 * (i & 3);
        s16x8 bfr = *(const s16x8*)&Whh[(nt * 16 + cc) * 256 + kt * 32 + qq * 8];
        acc[0][i] = __builtin_amdgcn_mfma_f32_16x16x32_bf16(a0, bfr, acc[0][i], 0, 0, 0);
        acc[1][i] = __builtin_amdgcn_mfma_f32_16x16x32_bf16(a1, bfr, acc[1][i], 0, 0, 0);
      }
    }
    __syncthreads();

#pragma unroll
    for (int mt = 0; mt < 2; ++mt)
#pragma unroll
      for (int a = 0; a < 4; ++a) {
        const int j = (w + 4 * a) * 16 + cc;
#pragma unroll
        for (int r = 0; r < 4; ++r) {
          const int m = mt * 16 + qq * 4 + r;
          const int li = mt * 4 + r;
          const unsigned short* pr = gx + (long)(m * 32 + t) * 1024;
          float gi = acc[mt][a][r]      + bf2f(pr[j])       + bv[a];
          float gf = acc[mt][4 + a][r]  + bf2f(pr[256 + j]) + bv[4 + a];
          float gg = acc[mt][8 + a][r]  + bf2f(pr[512 + j]) + bv[8 + a];
          float go = acc[mt][12 + a][r] + bf2f(pr[768 + j]) + bv[12 + a];
          unsigned short hb16 = 0;
          if (t < lenr[li]) {
            const int ci = mt * 16 + a * 4 + r;
            float cn = sigm(gf) * cst[ci] + sigm(gi) * tanh_(gg);
            cst[ci] = cn;
            float hn = sigm(go) * tanh_(cn);
            hb16 = f2bf(hn);
            hly[m * 264 + j] = hb16;
          }
          ch[(long)(m * 32 + t) * 512 + dir * 256 + j] = hb16;  // 0 at pad steps
        }
      }
  }
}

// ---------------------------------------------------------------------------
// K8: out[n][k] = ch[n][:] . fc_W[k][:] + fc_b[k]. One wave per row.
__global__ __launch_bounds__(64)
void fc_kernel(const unsigned short* __restrict__ ch, const float* __restrict__ W,
               const float* __restrict__ bfc, float* __restrict__ out) {
  const int n = blockIdx.x, lane = threadIdx.x;
  float xv[8];
  const unsigned short* cp = ch + (long)n * 512 + lane * 8;
#pragma unroll
  for (int i = 0; i < 8; ++i) xv[i] = bf2f(cp[i]);
  float s[9];
#pragma unroll
  for (int k = 0; k < 9; ++k) {
    const float* wr = W + k * 512 + lane * 8;
    float t = 0.f;
#pragma unroll
    for (int i = 0; i < 8; ++i) t += xv[i] * wr[i];
    s[k] = t;
  }
#pragma unroll
  for (int off = 32; off; off >>= 1)
#pragma unroll
    for (int k = 0; k < 9; ++k) s[k] += __shfl_down(s[k], off, 64);
  if (lane == 0) {
#pragma unroll
    for (int k = 0; k < 9; ++k) out[n * 9 + k] = s[k] + bfc[k];
  }
}

// ---------------------------------------------------------------------------
extern "C" void kernel_launch(void* const* d_in, const int* in_sizes, int n_in,
                              void* d_out, int out_size, void* d_ws, size_t ws_size,
                              hipStream_t stream) {
  const int*   x           = (const int*)d_in[0];
  const int*   x_len       = (const int*)d_in[2];
  const int*   x_chunk_len = (const int*)d_in[3];
  const float* emb         = (const float*)d_in[4];
  const float* tok_Wih_f   = (const float*)d_in[5];
  const float* tok_Whh_f   = (const float*)d_in[6];
  const float* tok_b_f     = (const float*)d_in[7];
  const float* tok_Wih_b   = (const float*)d_in[8];
  // d_in[9] tok_Whh_b: unused (reverse masked scan at t=clen-1 starts from zero state)
  const float* tok_b_b     = (const float*)d_in[10];
  const float* chk_Wih_f   = (const float*)d_in[11];
  const float* chk_Whh_f   = (const float*)d_in[12];
  const float* chk_b_f     = (const float*)d_in[13];
  const float* chk_Wih_b   = (const float*)d_in[14];
  const float* chk_Whh_b   = (const float*)d_in[15];
  const float* chk_b_b     = (const float*)d_in[16];
  const float* fc_W        = (const float*)d_in[17];
  const float* fc_b        = (const float*)d_in[18];
  float* out = (float*)d_out;

  char* ws = (char*)d_ws;
  size_t off = 0;
  auto alloc = [&](size_t bytes) -> void* {
    void* p = ws + off;
    off += (bytes + 255) & ~(size_t)255;
    return p;
  };
  unsigned short* Wf   = (unsigned short*)alloc((size_t)1024 * 320 * 2);
  unsigned short* Wb   = (unsigned short*)alloc((size_t)1024 * 320 * 2);
  unsigned short* Whhf = (unsigned short*)alloc((size_t)1024 * 256 * 2);
  unsigned short* Wcf  = (unsigned short*)alloc((size_t)1024 * 512 * 2);
  unsigned short* Wcb  = (unsigned short*)alloc((size_t)1024 * 512 * 2);
  unsigned short* Whcf = (unsigned short*)alloc((size_t)1024 * 256 * 2);
  unsigned short* Whcb = (unsigned short*)alloc((size_t)1024 * 256 * 2);
  unsigned short* proj = (unsigned short*)alloc((size_t)30000 * 1024 * 2);
  unsigned short* gxbb = (unsigned short*)alloc((size_t)1024 * 1024 * 2);
  unsigned short* gxcf = (unsigned short*)alloc((size_t)1024 * 1024 * 2);
  unsigned short* gxcb = (unsigned short*)alloc((size_t)1024 * 1024 * 2);
  float*          chunks = (float*)alloc((size_t)1024 * 512 * 4);
  unsigned short* cho  = (unsigned short*)alloc((size_t)1024 * 512 * 2);
  int* clens = (int*)alloc(1024 * 4);
  int* lastv = (int*)alloc(1024 * 4);
  int* order = (int*)alloc(1024 * 4);
  int* glen  = (int*)alloc(32 * 4);

  prep_weights<<<dim3(1024, 7), 256, 0, stream>>>(
      tok_Wih_f, tok_Wih_b, tok_Whh_f, chk_Wih_f, chk_Wih_b, chk_Whh_f, chk_Whh_b,
      Wf, Wb, Whhf, Wcf, Wcb, Whcf, Whcb);
  prep_small<<<1, 1024, 0, stream>>>(x, x_chunk_len, clens, lastv, order, glen);

  // vocab pre-projection: proj = emb x tok_Wih_f^T
  gemm_bf<<<dim3(4, 235), 256, 0, stream>>>(emb, nullptr, 30000, 300, 300, 320, Wf, proj);
  // backward gx for last tokens only
  gemm_bf<<<dim3(4, 8), 256, 0, stream>>>(emb, lastv, 1024, 300, 300, 320, Wb, gxbb);
  bwd_step<<<1024, 256, 0, stream>>>(gxbb, tok_b_b, chunks);
  // forward token recurrence
  tok_fwd<<<32, 256, 0, stream>>>(proj, Whhf, tok_b_f, x, order, clens, glen, chunks);
  // chunk-level input projections
  gemm_bf<<<dim3(4, 8), 256, 0, stream>>>(chunks, nullptr, 1024, 512, 512, 512, Wcf, gxcf);
  gemm_bf<<<dim3(4, 8), 256, 0, stream>>>(chunks, nullptr, 1024, 512, 512, 512, Wcb, gxcb);
  // chunk BiLSTM (fwd block 0, bwd block 1)
  chunk_rec<<<2, 256, 0, stream>>>(gxcf, gxcb, Whcf, Whcb, chk_b_f, chk_b_b, x_len, cho);
  // final FC
  fc_kernel<<<1024, 64, 0, stream>>>(cho, fc_W, fc_b, out);
}

// Round 2
// 2095.987 us; speedup vs baseline: 1.5673x; 1.5673x over previous
//
#include <hip/hip_runtime.h>

// ---------------------------------------------------------------------------
// HierarchicalBiLSTM_CRF on MI355X (gfx950) — round 2
//
//  K0a prep_weights : cast/pad weights to bf16
//  K0b prep_small   : clens, last-token ids, counting-sort seqs by len (desc)
//  K1  gemm_bf      : proj[30000][1024] = emb x tok_Wih_f^T   (vocab pre-proj)
//  K2  gemm_bf      : gxb[1024][1024]   = emb[last tok] x tok_Wih_b^T
//  K3  bwd_step     : 1-step reverse LSTM -> chunks[:,256:512]
//  K4  gather_gx    : gx[p][t][j*4+g] = proj[x[seq][t]][g*256+j]  (gate-packed)
//  K5  tok_fwd      : forward token LSTM, 32 blocks x 1024 thr (16 waves)
//  K6  gemm_bf x2   : gxc_{f,b} = chunks x chk_Wih_{f,b}^T
//  K6b repack4      : gate-pack gxc_{f,b}
//  K7  chunk_rec    : chunk BiLSTM, 2 blocks x 1024 thr
//  K8  fc_kernel    : out = ch x fc_W^T + fc_b
// ---------------------------------------------------------------------------

typedef __attribute__((ext_vector_type(8))) short s16x8;
typedef __attribute__((ext_vector_type(4))) float f32x4;
typedef __attribute__((ext_vector_type(2))) unsigned int u32x2;

__device__ __forceinline__ unsigned short f2bf(float f) {
  unsigned u = __builtin_bit_cast(unsigned, f);
  u += 0x7fff + ((u >> 16) & 1);   // RNE
  return (unsigned short)(u >> 16);
}
__device__ __forceinline__ float bf2f(unsigned short h) {
  unsigned u = ((unsigned)h) << 16;
  return __builtin_bit_cast(float, u);
}
__device__ __forceinline__ float sigm(float x) { return 1.f / (1.f + __expf(-x)); }
__device__ __forceinline__ float tanh_(float x) { return 1.f - 2.f / (__expf(2.f * x) + 1.f); }

union PK8 { s16x8 v; unsigned short u[8]; };

// ---------------------------------------------------------------------------
__global__ void prep_weights(const float* __restrict__ wihf, const float* __restrict__ wihb,
                             const float* __restrict__ whhf,
                             const float* __restrict__ wcf, const float* __restrict__ wcb,
                             const float* __restrict__ whcf, const float* __restrict__ whcb,
                             unsigned short* __restrict__ o_wf, unsigned short* __restrict__ o_wb,
                             unsigned short* __restrict__ o_whhf,
                             unsigned short* __restrict__ o_wcf, unsigned short* __restrict__ o_wcb,
                             unsigned short* __restrict__ o_whcf, unsigned short* __restrict__ o_whcb) {
  const int job = blockIdx.y, r = blockIdx.x, tid = threadIdx.x;
  const float* src; unsigned short* dst; int Ks, Kd;
  switch (job) {
    case 0: src = wihf; dst = o_wf;   Ks = 300; Kd = 320; break;
    case 1: src = wihb; dst = o_wb;   Ks = 300; Kd = 320; break;
    case 2: src = whhf; dst = o_whhf; Ks = 256; Kd = 256; break;
    case 3: src = wcf;  dst = o_wcf;  Ks = 512; Kd = 512; break;
    case 4: src = wcb;  dst = o_wcb;  Ks = 512; Kd = 512; break;
    case 5: src = whcf; dst = o_whcf; Ks = 256; Kd = 256; break;
    default:src = whcb; dst = o_whcb; Ks = 256; Kd = 256; break;
  }
  for (int c = tid; c < Kd; c += 256)
    dst[r * Kd + c] = f2bf(c < Ks ? src[r * Ks + c] : 0.f);
}

// ---------------------------------------------------------------------------
__global__ void prep_small(const int* __restrict__ x, const int* __restrict__ xcl,
                           int* __restrict__ clens, int* __restrict__ lastv,
                           int* __restrict__ order, int* __restrict__ glen) {
  __shared__ int start[65];
  const int n = threadIdx.x;  // 1024 threads
  if (n < 65) start[n] = 0;
  __syncthreads();
  int len = xcl[n]; len = len < 1 ? 1 : (len > 64 ? 64 : len);
  clens[n] = len;
  lastv[n] = x[n * 64 + len - 1];
  atomicAdd(&start[len], 1);
  __syncthreads();
  if (n == 0) {
    int acc = 0;
    for (int l = 64; l >= 1; --l) { int h = start[l]; start[l] = acc; acc += h; }
  }
  __syncthreads();
  int pos = atomicAdd(&start[len], 1);
  order[pos] = n;
  __syncthreads();
  if (n < 32) glen[n] = clens[order[n * 32]];   // descending -> first = group max
}

// ---------------------------------------------------------------------------
// Unified GEMM: C[M][1024](bf16) = A(rows via rowmap)[M][Klog](f32) x B[1024][KP](bf16)^T
__global__ __launch_bounds__(256, 2)
void gemm_bf(const float* __restrict__ A, const int* __restrict__ rowmap,
             int Mrows, int Astride, int Klog, int KP,
             const unsigned short* __restrict__ B, unsigned short* __restrict__ C) {
  __shared__ unsigned short As[128 * 40];
  __shared__ unsigned short Ep[4][64 * 136];
  const int tid = threadIdx.x;
  const int lane = tid & 63, w = tid >> 6;
  const int wrow = w >> 1, wcol = w & 1;
  const int cc = lane & 15, qq = lane >> 4;
  const int m0 = blockIdx.y * 128, n0 = blockIdx.x * 256;

  f32x4 zz = {0.f, 0.f, 0.f, 0.f};
  f32x4 acc[4][8];
#pragma unroll
  for (int i = 0; i < 4; ++i)
#pragma unroll
    for (int j = 0; j < 8; ++j) acc[i][j] = zz;

  const int arow = tid >> 1, ahalf = tid & 1;
  const float* arp = nullptr;
  {
    int av = m0 + arow;
    if (av < Mrows) {
      int amap = rowmap ? rowmap[av] : av;
      arp = A + (long)amap * Astride;
    }
  }

  const int nktiles = KP >> 5;
  for (int kt = 0; kt < nktiles; ++kt) {
    const int k0 = kt << 5;
    __syncthreads();
    {
      const int kb = k0 + ahalf * 16;
      unsigned short hv[16];
      if (arp && kb + 16 <= Klog) {
        const float* p = arp + kb;
#pragma unroll
        for (int i = 0; i < 16; i += 4) {
          f32x4 t = *(const f32x4*)(p + i);
          hv[i] = f2bf(t.x); hv[i + 1] = f2bf(t.y);
          hv[i + 2] = f2bf(t.z); hv[i + 3] = f2bf(t.w);
        }
      } else {
#pragma unroll
        for (int i = 0; i < 16; ++i) {
          float v = (arp && (kb + i) < Klog) ? arp[kb + i] : 0.f;
          hv[i] = f2bf(v);
        }
      }
      PK8 p0, p1;
#pragma unroll
      for (int i = 0; i < 8; ++i) { p0.u[i] = hv[i]; p1.u[i] = hv[8 + i]; }
      *(s16x8*)&As[arow * 40 + ahalf * 16] = p0.v;
      *(s16x8*)&As[arow * 40 + ahalf * 16 + 8] = p1.v;
    }
    __syncthreads();
    s16x8 af[4];
#pragma unroll
    for (int mt = 0; mt < 4; ++mt)
      af[mt] = *(const s16x8*)&As[(wrow * 64 + mt * 16 + cc) * 40 + qq * 8];
#pragma unroll
    for (int nt = 0; nt < 8; ++nt) {
      const unsigned short* bp = B + (long)(n0 + wcol * 128 + nt * 16 + cc) * KP + k0 + qq * 8;
      s16x8 bfr = *(const s16x8*)bp;
#pragma unroll
      for (int mt = 0; mt < 4; ++mt)
        acc[mt][nt] = __builtin_amdgcn_mfma_f32_16x16x32_bf16(af[mt], bfr, acc[mt][nt], 0, 0, 0);
    }
  }
  __syncthreads();
#pragma unroll
  for (int mt = 0; mt < 4; ++mt)
#pragma unroll
    for (int nt = 0; nt < 8; ++nt)
#pragma unroll
      for (int r = 0; r < 4; ++r)
        Ep[w][(mt * 16 + qq * 4 + r) * 136 + nt * 16 + cc] = f2bf(acc[mt][nt][r]);
  __syncthreads();
#pragma unroll
  for (int it = 0; it < 16; ++it) {
    int row = it * 4 + qq;
    s16x8 d = *(const s16x8*)&Ep[w][row * 136 + cc * 8];
    int gm = m0 + wrow * 64 + row;
    int gn = n0 + wcol * 128 + cc * 8;
    if (gm < Mrows) *(s16x8*)&C[(long)gm * 1024 + gn] = d;
  }
}

// ---------------------------------------------------------------------------
__global__ void bwd_step(const unsigned short* __restrict__ gxb,
                         const float* __restrict__ bias,
                         float* __restrict__ chunks) {
  const int n = blockIdx.x, j = threadIdx.x;  // 1024 x 256
  const unsigned short* row = gxb + (long)n * 1024;
  float gi = bf2f(row[j]) + bias[j];
  float gg = bf2f(row[512 + j]) + bias[512 + j];
  float go = bf2f(row[768 + j]) + bias[768 + j];
  float cn = sigm(gi) * tanh_(gg);
  chunks[(long)n * 512 + 256 + j] = sigm(go) * tanh_(cn);
}

// ---------------------------------------------------------------------------
// K4: pre-gather gate projections for the forward token recurrence.
// gx[p][t][j*4+g] (bf16), p = sorted position. Zero-filled for t >= len.
__global__ __launch_bounds__(256)
void gather_gx(const unsigned short* __restrict__ proj, const int* __restrict__ x,
               const int* __restrict__ order, const int* __restrict__ clens,
               unsigned short* __restrict__ gx) {
  const int t = blockIdx.x, p = blockIdx.y, j = threadIdx.x;
  const int seq = order[p];
  const int len = clens[seq];
  unsigned short* dst = gx + ((size_t)p * 64 + t) * 1024 + j * 4;
  if (t >= len) { u32x2 z = {0u, 0u}; *(u32x2*)dst = z; return; }
  const int tok = x[seq * 64 + t];
  const unsigned short* src = proj + (size_t)tok * 1024 + j;
  unsigned v0 = src[0], v1 = src[256], v2 = src[512], v3 = src[768];
  u32x2 pk = {v0 | (v1 << 16), v2 | (v3 << 16)};
  *(u32x2*)dst = pk;
}

// ---------------------------------------------------------------------------
// K6b: gate-pack gxc: dst[r][j*4+g] = src[r][g*256+j]
__global__ __launch_bounds__(256)
void repack4(const unsigned short* __restrict__ s0, const unsigned short* __restrict__ s1,
             unsigned short* __restrict__ d0, unsigned short* __restrict__ d1) {
  const int r = blockIdx.x, j = threadIdx.x;
  const unsigned short* s = (blockIdx.y ? s1 : s0) + (size_t)r * 1024;
  unsigned short* d = (blockIdx.y ? d1 : d0) + (size_t)r * 1024 + j * 4;
  unsigned v0 = s[j], v1 = s[256 + j], v2 = s[512 + j], v3 = s[768 + j];
  u32x2 pk = {v0 | (v1 << 16), v2 | (v3 << 16)};
  *(u32x2*)d = pk;
}

// ---------------------------------------------------------------------------
// K5: forward token LSTM recurrence. 32 blocks x 1024 threads (16 waves).
// Wave w owns j-slice j = w*16+cc across all 4 gates (n-tiles g*16+w) ->
// every lane holds i,f,g,o for its (m,j) -> register-local c/h update.
__global__ __launch_bounds__(1024)
void tok_fwd(const unsigned short* __restrict__ gx,     // [1024][64][1024] packed
             const unsigned short* __restrict__ Whh,    // [1024][256]
             const float* __restrict__ bias,
             const int* __restrict__ order,
             const int* __restrict__ clens,
             const int* __restrict__ glen,
             float* __restrict__ chunks) {
  __shared__ unsigned short hly[32 * 264];
  __shared__ int sg[32], slen[32];
  const int tid = threadIdx.x;
  const int lane = tid & 63, w = tid >> 6;
  const int cc = lane & 15, qq = lane >> 4;
  const int gb = blockIdx.x;

  if (tid < 32) {
    int s = order[gb * 32 + tid];
    sg[tid] = s;
    slen[tid] = clens[s];
  }
  for (int i = tid; i < 32 * 264; i += 1024) hly[i] = 0;
  const int maxlen = glen[gb];
  __syncthreads();

  const int j = w * 16 + cc;
  float bv[4];
#pragma unroll
  for (int g = 0; g < 4; ++g) bv[g] = bias[g * 256 + j];

  int lenr[8];
#pragma unroll
  for (int mt = 0; mt < 2; ++mt)
#pragma unroll
    for (int r = 0; r < 4; ++r) lenr[mt * 4 + r] = slen[mt * 16 + qq * 4 + r];

  float cst[8];
#pragma unroll
  for (int i = 0; i < 8; ++i) cst[i] = 0.f;

  // per-lane gx base (row = gb*32 + m)
  const unsigned short* gxb = gx + ((size_t)(gb * 32) * 64) * 1024 + j * 4;

  f32x4 zz = {0.f, 0.f, 0.f, 0.f};

  for (int t = 0; t < maxlen; ++t) {
    // prefetch this step's gate projections (independent of recurrence)
    u32x2 gxp[8];
#pragma unroll
    for (int mt = 0; mt < 2; ++mt)
#pragma unroll
      for (int r = 0; r < 4; ++r) {
        const int m = mt * 16 + qq * 4 + r;
        gxp[mt * 4 + r] = *(const u32x2*)(gxb + ((size_t)m * 64 + t) * 1024);
      }

    __syncthreads();   // A: prev-step h writes visible

    f32x4 acc[2][4];
#pragma unroll
    for (int mt = 0; mt < 2; ++mt)
#pragma unroll
      for (int g = 0; g < 4; ++g) acc[mt][g] = zz;

#pragma unroll
    for (int kt = 0; kt < 8; ++kt) {
      s16x8 a0 = *(const s16x8*)&hly[cc * 264 + kt * 32 + qq * 8];
      s16x8 a1 = *(const s16x8*)&hly[(16 + cc) * 264 + kt * 32 + qq * 8];
#pragma unroll
      for (int g = 0; g < 4; ++g) {
        const int nt = g * 16 + w;
        s16x8 bfr = *(const s16x8*)&Whh[(size_t)(nt * 16 + cc) * 256 + kt * 32 + qq * 8];
        acc[0][g] = __builtin_amdgcn_mfma_f32_16x16x32_bf16(a0, bfr, acc[0][g], 0, 0, 0);
        acc[1][g] = __builtin_amdgcn_mfma_f32_16x16x32_bf16(a1, bfr, acc[1][g], 0, 0, 0);
      }
    }
    __syncthreads();   // B: MFMA h reads done

#pragma unroll
    for (int mt = 0; mt < 2; ++mt)
#pragma unroll
      for (int r = 0; r < 4; ++r) {
        const int m = mt * 16 + qq * 4 + r;
        const int li = mt * 4 + r;
        const u32x2 pk = gxp[li];
        float gi = acc[mt][0][r] + bf2f((unsigned short)(pk.x & 0xffff)) + bv[0];
        float gf = acc[mt][1][r] + bf2f((unsigned short)(pk.x >> 16)) + bv[1];
        float gg = acc[mt][2][r] + bf2f((unsigned short)(pk.y & 0xffff)) + bv[2];
        float go = acc[mt][3][r] + bf2f((unsigned short)(pk.y >> 16)) + bv[3];
        if (t < lenr[li]) {
          float cn = sigm(gf) * cst[li] + sigm(gi) * tanh_(gg);
          cst[li] = cn;
          float hn = sigm(go) * tanh_(cn);
          hly[m * 264 + j] = f2bf(hn);
          if (t == lenr[li] - 1) chunks[(size_t)sg[m] * 512 + j] = hn;
        }
      }
  }
}

// ---------------------------------------------------------------------------
// K7: chunk-level BiLSTM. 2 blocks (dir) x 1024 threads (16 waves).
__global__ __launch_bounds__(1024)
void chunk_rec(const unsigned short* __restrict__ gxf,   // packed [n*32+t][1024]
               const unsigned short* __restrict__ gxb,
               const unsigned short* __restrict__ Whf,
               const unsigned short* __restrict__ Whb,
               const float* __restrict__ bf_, const float* __restrict__ bb_,
               const int* __restrict__ xlen,
               unsigned short* __restrict__ ch) {
  __shared__ unsigned short hly[32 * 264];
  const int tid = threadIdx.x;
  const int lane = tid & 63, w = tid >> 6;
  const int cc = lane & 15, qq = lane >> 4;
  const int dir = blockIdx.x;
  const unsigned short* gx = dir ? gxb : gxf;
  const unsigned short* Whh = dir ? Whb : Whf;
  const float* bias = dir ? bb_ : bf_;

  for (int i = tid; i < 32 * 264; i += 1024) hly[i] = 0;
  __syncthreads();

  const int j = w * 16 + cc;
  float bv[4];
#pragma unroll
  for (int g = 0; g < 4; ++g) bv[g] = bias[g * 256 + j];

  int lenr[8];
#pragma unroll
  for (int mt = 0; mt < 2; ++mt)
#pragma unroll
    for (int r = 0; r < 4; ++r) {
      int L = xlen[mt * 16 + qq * 4 + r];
      lenr[mt * 4 + r] = L > 32 ? 32 : L;
    }

  float cst[8];
#pragma unroll
  for (int i = 0; i < 8; ++i) cst[i] = 0.f;

  f32x4 zz = {0.f, 0.f, 0.f, 0.f};

  for (int tt = 0; tt < 32; ++tt) {
    const int t = dir ? (31 - tt) : tt;

    u32x2 gxp[8];
#pragma unroll
    for (int mt = 0; mt < 2; ++mt)
#pragma unroll
      for (int r = 0; r < 4; ++r) {
        const int m = mt * 16 + qq * 4 + r;
        gxp[mt * 4 + r] = *(const u32x2*)(gx + (size_t)(m * 32 + t) * 1024 + j * 4);
      }

    __syncthreads();

    f32x4 acc[2][4];
#pragma unroll
    for (int mt = 0; mt < 2; ++mt)
#pragma unroll
      for (int g = 0; g < 4; ++g) acc[mt][g] = zz;

#pragma unroll
    for (int kt = 0; kt < 8; ++kt) {
      s16x8 a0 = *(const s16x8*)&hly[cc * 264 + kt * 32 + qq * 8];
      s16x8 a1 = *(const s16x8*)&hly[(16 + cc) * 264 + kt * 32 + qq * 8];
#pragma unroll
      for (int g = 0; g < 4; ++g) {
        const int nt = g * 16 + w;
        s16x8 bfr = *(const s16x8*)&Whh[(size_t)(nt * 16 + cc) * 256 + kt * 32 + qq * 8];
        acc[0][g] = __builtin_amdgcn_mfma_f32_16x16x32_bf16(a0, bfr, acc[0][g], 0, 0, 0);
        acc[1][g] = __builtin_amdgcn_mfma_f32_16x16x32_bf16(a1, bfr, acc[1][g], 0, 0, 0);
      }
    }
    __syncthreads();

#pragma unroll
    for (int mt = 0; mt < 2; ++mt)
#pragma unroll
      for (int r = 0; r < 4; ++r) {
        const int m = mt * 16 + qq * 4 + r;
        const int li = mt * 4 + r;
        const u32x2 pk = gxp[li];
        float gi = acc[mt][0][r] + bf2f((unsigned short)(pk.x & 0xffff)) + bv[0];
        float gf = acc[mt][1][r] + bf2f((unsigned short)(pk.x >> 16)) + bv[1];
        float gg = acc[mt][2][r] + bf2f((unsigned short)(pk.y & 0xffff)) + bv[2];
        float go = acc[mt][3][r] + bf2f((unsigned short)(pk.y >> 16)) + bv[3];
        unsigned short hb16 = 0;
        if (t < lenr[li]) {
          float cn = sigm(gf) * cst[li] + sigm(gi) * tanh_(gg);
          cst[li] = cn;
          float hn = sigm(go) * tanh_(cn);
          hb16 = f2bf(hn);
          hly[m * 264 + j] = hb16;
        }
        ch[(size_t)(m * 32 + t) * 512 + dir * 256 + j] = hb16;
      }
  }
}

// ---------------------------------------------------------------------------
__global__ __launch_bounds__(64)
void fc_kernel(const unsigned short* __restrict__ ch, const float* __restrict__ W,
               const float* __restrict__ bfc, float* __restrict__ out) {
  const int n = blockIdx.x, lane = threadIdx.x;
  float xv[8];
  const unsigned short* cp = ch + (long)n * 512 + lane * 8;
#pragma unroll
  for (int i = 0; i < 8; ++i) xv[i] = bf2f(cp[i]);
  float s[9];
#pragma unroll
  for (int k = 0; k < 9; ++k) {
    const float* wr = W + k * 512 + lane * 8;
    float t = 0.f;
#pragma unroll
    for (int i = 0; i < 8; ++i) t += xv[i] * wr[i];
    s[k] = t;
  }
#pragma unroll
  for (int off = 32; off; off >>= 1)
#pragma unroll
    for (int k = 0; k < 9; ++k) s[k] += __shfl_down(s[k], off, 64);
  if (lane == 0) {
#pragma unroll
    for (int k = 0; k < 9; ++k) out[n * 9 + k] = s[k] + bfc[k];
  }
}

// ---------------------------------------------------------------------------
extern "C" void kernel_launch(void* const* d_in, const int* in_sizes, int n_in,
                              void* d_out, int out_size, void* d_ws, size_t ws_size,
                              hipStream_t stream) {
  const int*   x           = (const int*)d_in[0];
  const int*   x_len       = (const int*)d_in[2];
  const int*   x_chunk_len = (const int*)d_in[3];
  const float* emb         = (const float*)d_in[4];
  const float* tok_Wih_f   = (const float*)d_in[5];
  const float* tok_Whh_f   = (const float*)d_in[6];
  const float* tok_b_f     = (const float*)d_in[7];
  const float* tok_Wih_b   = (const float*)d_in[8];
  // d_in[9] tok_Whh_b: unused (reverse masked scan at t=clen-1 starts from zero state)
  const float* tok_b_b     = (const float*)d_in[10];
  const float* chk_Wih_f   = (const float*)d_in[11];
  const float* chk_Whh_f   = (const float*)d_in[12];
  const float* chk_b_f     = (const float*)d_in[13];
  const float* chk_Wih_b   = (const float*)d_in[14];
  const float* chk_Whh_b   = (const float*)d_in[15];
  const float* chk_b_b     = (const float*)d_in[16];
  const float* fc_W        = (const float*)d_in[17];
  const float* fc_b        = (const float*)d_in[18];
  float* out = (float*)d_out;

  char* ws = (char*)d_ws;
  size_t off = 0;
  auto alloc = [&](size_t bytes) -> void* {
    void* p = ws + off;
    off += (bytes + 255) & ~(size_t)255;
    return p;
  };
  unsigned short* Wf   = (unsigned short*)alloc((size_t)1024 * 320 * 2);
  unsigned short* Wb   = (unsigned short*)alloc((size_t)1024 * 320 * 2);
  unsigned short* Whhf = (unsigned short*)alloc((size_t)1024 * 256 * 2);
  unsigned short* Wcf  = (unsigned short*)alloc((size_t)1024 * 512 * 2);
  unsigned short* Wcb  = (unsigned short*)alloc((size_t)1024 * 512 * 2);
  unsigned short* Whcf = (unsigned short*)alloc((size_t)1024 * 256 * 2);
  unsigned short* Whcb = (unsigned short*)alloc((size_t)1024 * 256 * 2);
  unsigned short* proj = (unsigned short*)alloc((size_t)30000 * 1024 * 2);
  unsigned short* gxbb = (unsigned short*)alloc((size_t)1024 * 1024 * 2);
  unsigned short* gxcf = (unsigned short*)alloc((size_t)1024 * 1024 * 2);
  unsigned short* gxcb = (unsigned short*)alloc((size_t)1024 * 1024 * 2);
  unsigned short* gxcfp= (unsigned short*)alloc((size_t)1024 * 1024 * 2);
  unsigned short* gxcbp= (unsigned short*)alloc((size_t)1024 * 1024 * 2);
  float*          chunks = (float*)alloc((size_t)1024 * 512 * 4);
  unsigned short* cho  = (unsigned short*)alloc((size_t)1024 * 512 * 2);
  unsigned short* gxs  = (unsigned short*)alloc((size_t)1024 * 64 * 1024 * 2);  // 134 MB
  int* clens = (int*)alloc(1024 * 4);
  int* lastv = (int*)alloc(1024 * 4);
  int* order = (int*)alloc(1024 * 4);
  int* glen  = (int*)alloc(32 * 4);

  prep_weights<<<dim3(1024, 7), 256, 0, stream>>>(
      tok_Wih_f, tok_Wih_b, tok_Whh_f, chk_Wih_f, chk_Wih_b, chk_Whh_f, chk_Whh_b,
      Wf, Wb, Whhf, Wcf, Wcb, Whcf, Whcb);
  prep_small<<<1, 1024, 0, stream>>>(x, x_chunk_len, clens, lastv, order, glen);

  // vocab pre-projection: proj = emb x tok_Wih_f^T
  gemm_bf<<<dim3(4, 235), 256, 0, stream>>>(emb, nullptr, 30000, 300, 300, 320, Wf, proj);
  // backward gx for last tokens only
  gemm_bf<<<dim3(4, 8), 256, 0, stream>>>(emb, lastv, 1024, 300, 300, 320, Wb, gxbb);
  bwd_step<<<1024, 256, 0, stream>>>(gxbb, tok_b_b, chunks);
  // pre-gather forward gate projections (gate-packed, sorted order)
  gather_gx<<<dim3(64, 1024), 256, 0, stream>>>(proj, x, order, clens, gxs);
  // forward token recurrence
  tok_fwd<<<32, 1024, 0, stream>>>(gxs, Whhf, tok_b_f, order, clens, glen, chunks);
  // chunk-level input projections
  gemm_bf<<<dim3(4, 8), 256, 0, stream>>>(chunks, nullptr, 1024, 512, 512, 512, Wcf, gxcf);
  gemm_bf<<<dim3(4, 8), 256, 0, stream>>>(chunks, nullptr, 1024, 512, 512, 512, Wcb, gxcb);
  repack4<<<dim3(1024, 2), 256, 0, stream>>>(gxcf, gxcb, gxcfp, gxcbp);
  // chunk BiLSTM (fwd block 0, bwd block 1)
  chunk_rec<<<2, 1024, 0, stream>>>(gxcfp, gxcbp, Whcf, Whcb, chk_b_f, chk_b_b, x_len, cho);
  // final FC
  fc_kernel<<<1024, 64, 0, stream>>>(cho, fc_W, fc_b, out);
}